// Round 11
// baseline (53.976 us; speedup 1.0000x reference)
//
#include <hip/hip_runtime.h>
#include <math.h>

#define NQ 8
#define DEPTH 3
#define FDIM 16
#define HDIM 256
#define WAVES_PER_BLOCK 4
#define THREADS 256
#define ROWS_PER_BLOCK 16          // 4 waves x 4 rows/wave
#define NGATE (NQ * DEPTH)         // 24

// ---------------- DPP helpers ----------------
template<int CTRL>
__device__ __forceinline__ float dpp1(float v) {
    return __int_as_float(__builtin_amdgcn_update_dpp(
        0, __float_as_int(v), CTRL, 0xF, 0xF, true));
}

// xor-mask shuffle within each 16-lane row, any 4-bit mask (R4-validated table)
template<int M4>
__device__ __forceinline__ float dppx(float v) {
    if constexpr (M4 == 0)  return v;
    else if constexpr (M4 == 1)  return dpp1<0xB1>(v);
    else if constexpr (M4 == 2)  return dpp1<0x4E>(v);
    else if constexpr (M4 == 3)  return dpp1<0x1B>(v);
    else if constexpr (M4 == 4)  return dpp1<0x1B>(dpp1<0x141>(v));
    else if constexpr (M4 == 5)  return dpp1<0x4E>(dpp1<0x141>(v));
    else if constexpr (M4 == 6)  return dpp1<0xB1>(dpp1<0x141>(v));
    else if constexpr (M4 == 7)  return dpp1<0x141>(v);
    else if constexpr (M4 == 8)  return dpp1<0x128>(v);
    else if constexpr (M4 == 9)  return dpp1<0xB1>(dpp1<0x128>(v));
    else if constexpr (M4 == 10) return dpp1<0x4E>(dpp1<0x128>(v));
    else if constexpr (M4 == 11) return dpp1<0x1B>(dpp1<0x128>(v));
    else if constexpr (M4 == 12) return dpp1<0x1B>(dpp1<0x140>(v));
    else if constexpr (M4 == 13) return dpp1<0x4E>(dpp1<0x140>(v));
    else if constexpr (M4 == 14) return dpp1<0xB1>(dpp1<0x140>(v));
    else                         return dpp1<0x140>(v);
}

// value from lane^16 / lane^32 (R3-verified select form)
__device__ __forceinline__ float px16v(float v, int lane) {
#if __has_builtin(__builtin_amdgcn_permlane16_swap)
    auto r = __builtin_amdgcn_permlane16_swap(__float_as_int(v), __float_as_int(v), false, false);
    return __int_as_float((lane & 16) ? r[0] : r[1]);
#else
    return __shfl_xor(v, 16, 64);
#endif
}
__device__ __forceinline__ float px32v(float v, int lane) {
#if __has_builtin(__builtin_amdgcn_permlane32_swap)
    auto r = __builtin_amdgcn_permlane32_swap(__float_as_int(v), __float_as_int(v), false, false);
    return __int_as_float((lane & 32) ? r[0] : r[1]);
#else
    return __shfl_xor(v, 32, 64);
#endif
}

// full 64-lane sum (validated R5+): no-select permlane trick for 16/32
__device__ __forceinline__ float wred(float v, int lane) {
    v += dppx<1>(v);
    v += dppx<2>(v);
    v += dppx<4>(v);
    v += dppx<8>(v);
#if __has_builtin(__builtin_amdgcn_permlane16_swap)
    {
        auto r = __builtin_amdgcn_permlane16_swap(__float_as_int(v), __float_as_int(v), false, false);
        v = __int_as_float(r[0]) + __int_as_float(r[1]);
    }
#else
    v += __shfl_xor(v, 16, 64);
#endif
#if __has_builtin(__builtin_amdgcn_permlane32_swap)
    {
        auto r = __builtin_amdgcn_permlane32_swap(__float_as_int(v), __float_as_int(v), false, false);
        v = __int_as_float(r[0]) + __int_as_float(r[1]);
    }
#else
    v += __shfl_xor(v, 32, 64);
#endif
    return v;
}

__device__ __forceinline__ float fast_tanh(float y) {
    float ex = __expf(2.f * y);
    return 1.f - 2.f * __builtin_amdgcn_rcpf(ex + 1.f);
}

// ---------------- merged RZ*RY gate, 4-rows-per-wave layout ----------------
// amp = (k<<4)|g, g = lane&15 (16-lane row), k = register index 0..15.
// Reg part of mask: k' = k ^ (M>>4) (free). Lane part: DPP xor (M&15).
// Algebra identical to R10 (verified): amp' = L*amp + P*amp(x^M),
//   L = a0 + i*eta*a1, P = eta*b0 - i*b1, eta = parity(amp & R) ? + : -.
template<int M, int R>
__device__ __forceinline__ void gateq(float (&kr)[16], float (&ki)[16],
                                      float a0, float a1, float b0, float b1,
                                      int g) {
    constexpr int MH = (M >> 4) & 15, ML = M & 15;
    constexpr int RH = (R >> 4) & 15, RL = R & 15;
    bool p0;
    if constexpr (RL == 0)                 p0 = false;
    else if constexpr ((RL & (RL-1)) == 0) p0 = (g & RL) != 0;
    else                                   p0 = (__popc(g & RL) & 1) != 0;
    float ea1 = p0 ? a1 : -a1;
    float eb0 = p0 ? b0 : -b0;

    if constexpr (MH == 0) {
        // lane-only pairing: partner of reg k is shuffled reg k
#pragma unroll
        for (int k = 0; k < 16; k++) {
            float pr = dppx<ML>(kr[k]);
            float pi = dppx<ML>(ki[k]);
            const bool f = (__builtin_popcount(k & RH) & 1) != 0;
            float za1 = f ? -ea1 : ea1;
            float zb0 = f ? -eb0 : eb0;
            float lr = fmaf(-za1, ki[k], a0 * kr[k]);
            float li = fmaf( za1, kr[k], a0 * ki[k]);
            kr[k] = fmaf( b1, pi, fmaf(zb0, pr, lr));
            ki[k] = fmaf(-b1, pr, fmaf(zb0, pi, li));
        }
    } else {
        constexpr int HB = (MH & 8) ? 8 : (MH & 4) ? 4 : (MH & 2) ? 2 : 1;
#pragma unroll
        for (int k = 0; k < 16; k++) {
            if (k & HB) continue;            // one rep per {k, k^MH} pair
            const int k2 = k ^ MH;
            float pr1 = dppx<ML>(kr[k2]), pi1 = dppx<ML>(ki[k2]);   // partner of k
            float pr2 = dppx<ML>(kr[k]),  pi2 = dppx<ML>(ki[k]);    // partner of k2
            const bool f1 = (__builtin_popcount(k  & RH) & 1) != 0;
            const bool f2 = (__builtin_popcount(k2 & RH) & 1) != 0;
            float za1a = f1 ? -ea1 : ea1, zb0a = f1 ? -eb0 : eb0;
            float za1b = f2 ? -ea1 : ea1, zb0b = f2 ? -eb0 : eb0;
            float lra = fmaf(-za1a, ki[k],  a0 * kr[k]);
            float lia = fmaf( za1a, kr[k],  a0 * ki[k]);
            float lrb = fmaf(-za1b, ki[k2], a0 * kr[k2]);
            float lib = fmaf( za1b, kr[k2], a0 * ki[k2]);
            kr[k]  = fmaf( b1, pi1, fmaf(zb0a, pr1, lra));
            ki[k]  = fmaf(-b1, pr1, fmaf(zb0a, pi1, lia));
            kr[k2] = fmaf( b1, pi2, fmaf(zb0b, pr2, lrb));
            ki[k2] = fmaf(-b1, pr2, fmaf(zb0b, pi2, lib));
        }
    }
}

__global__ __launch_bounds__(THREADS) void hqcl_kernel(
    const float* __restrict__ x,     // (B,16)
    const float* __restrict__ w1,    // (256,16)
    const float* __restrict__ b1,    // (256)
    const float* __restrict__ w2,    // (8,256)
    const float* __restrict__ b2,    // (8)
    const float* __restrict__ qp,    // (48)
    const float* __restrict__ dw1,   // (256,1)
    const float* __restrict__ db1,   // (256)
    const float* __restrict__ dw2,   // (1,256)
    const float* __restrict__ db2,   // (1)
    float* __restrict__ out, int B)
{
    __shared__ float4 sG4[NGATE];            // (a0,a1,b0,b1) per gate
    __shared__ float  lds_u[ROWS_PER_BLOCK * NQ];   // u per row (revolutions)

    const int t = threadIdx.x;
    if (t < NGATE) {
        float cz, sz, cy, sy;
        __sincosf(qp[2 * t] * 0.5f,     &sz, &cz);
        __sincosf(qp[2 * t + 1] * 0.5f, &sy, &cy);
        sG4[t] = make_float4(cz * cy, sz * cy, cz * sy, sz * sy);
    }

    const int wave = t >> 6;
    const int lane = t & 63;
    const int rowbase = blockIdx.x * ROWS_PER_BLOCK + wave * 4;

    // ======== phase 1: encoder + angles, one row per wave, 4 sequential ========
#pragma unroll 1
    for (int rr = 0; rr < 4; rr++) {
        const int row = rowbase + rr;
        if (row >= B) break;
        const float4* xp = (const float4*)(x + row * FDIM);
        float4 x0 = xp[0], x1 = xp[1], x2 = xp[2], x3 = xp[3];

        float hreg[4];
#pragma unroll
        for (int m = 0; m < 4; m++) {
            int j = lane + 64 * m;
            const float4* wp = (const float4*)(w1 + j * FDIM);
            float4 wa = wp[0], wb = wp[1], wc = wp[2], wd = wp[3];
            float acc = b1[j];
            acc = fmaf(x0.x, wa.x, acc); acc = fmaf(x0.y, wa.y, acc);
            acc = fmaf(x0.z, wa.z, acc); acc = fmaf(x0.w, wa.w, acc);
            acc = fmaf(x1.x, wb.x, acc); acc = fmaf(x1.y, wb.y, acc);
            acc = fmaf(x1.z, wb.z, acc); acc = fmaf(x1.w, wb.w, acc);
            acc = fmaf(x2.x, wc.x, acc); acc = fmaf(x2.y, wc.y, acc);
            acc = fmaf(x2.z, wc.z, acc); acc = fmaf(x2.w, wc.w, acc);
            acc = fmaf(x3.x, wd.x, acc); acc = fmaf(x3.y, wd.y, acc);
            acc = fmaf(x3.z, wd.z, acc); acc = fmaf(x3.w, wd.w, acc);
            hreg[m] = fmaxf(acc, 0.f);
        }

        float myu = 0.f;
#pragma unroll
        for (int q = 0; q < NQ; q++) {
            float a = 0.f;
#pragma unroll
            for (int m = 0; m < 4; m++)
                a = fmaf(hreg[m], w2[q * HDIM + lane + 64 * m], a);
            a = wred(a, lane);
            float u = 0.25f * fast_tanh(a + b2[q]);   // half-angle in revolutions
            if (lane == q) myu = u;
        }
        if (lane < NQ) lds_u[(wave * 4 + rr) * NQ + lane] = myu;
    }
    __syncthreads();

    // ======== phase 2: circuit, 4 rows/wave, 16 lanes/row, DS-free gates ========
    const int g = lane & 15;
    const float* up = lds_u + ((wave << 2) | (lane >> 4)) * NQ;
    float4 uA = *(const float4*)(up);        // q0..3
    float4 uB = *(const float4*)(up + 4);    // q4..7

    float uu[8] = {uA.x, uA.y, uA.z, uA.w, uB.x, uB.y, uB.z, uB.w};
    float sv[8], cv[8];
#pragma unroll
    for (int q = 0; q < 8; q++) {
        asm("v_sin_f32 %0, %1" : "=v"(sv[q]) : "v"(uu[q]));
        asm("v_cos_f32 %0, %1" : "=v"(cv[q]) : "v"(uu[q]));
    }
    // lane product over q4..7 (g bit b <-> q = 7-b)
    float plg = ((g >> 3) & 1 ? sv[4] : cv[4]);
    plg *= ((g >> 2) & 1 ? sv[5] : cv[5]);
    plg *= ((g >> 1) & 1 ? sv[6] : cv[6]);
    plg *= ((g      ) & 1 ? sv[7] : cv[7]);
    // k-products (k bit 3,2 <-> q0,q1 ; k bit 1,0 <-> q2,q3)
    float q01[4] = {cv[0]*cv[1], cv[0]*sv[1], sv[0]*cv[1], sv[0]*sv[1]};
    float q23[4] = {cv[2]*cv[3], cv[2]*sv[3], sv[2]*cv[3], sv[2]*sv[3]};

    float kr[16], ki[16];
#pragma unroll
    for (int k = 0; k < 16; k++) {
        kr[k] = plg * q01[k >> 2] * q23[k & 3];
        ki[k] = 0.f;
    }

    // masks/parities: identical 8-bit constants to R5/R10 (verified), re-split (k,g)
#define GATE(L, Q, MM, RR) { float4 g4 = sG4[(L)*8 + (Q)]; \
        gateq<MM, RR>(kr, ki, g4.x, g4.y, g4.z, g4.w, g); }
    GATE(0,0,0x80,0x80) GATE(0,1,0x40,0x40) GATE(0,2,0x20,0x20) GATE(0,3,0x10,0x10)
    GATE(0,4,0x08,0x08) GATE(0,5,0x04,0x04) GATE(0,6,0x02,0x02) GATE(0,7,0x01,0x01)
    GATE(1,0,0xC0,0x7F) GATE(1,1,0x60,0xC0) GATE(1,2,0x30,0xE0) GATE(1,3,0x18,0xF0)
    GATE(1,4,0x0C,0xF8) GATE(1,5,0x06,0xFC) GATE(1,6,0x03,0xFE) GATE(1,7,0xC1,0xFF)
    GATE(2,0,0xA0,0xD5) GATE(2,1,0x50,0xBF) GATE(2,2,0x28,0x5F) GATE(2,3,0x14,0xAF)
    GATE(2,4,0x0A,0x57) GATE(2,5,0x05,0xAB) GATE(2,6,0xC2,0x55) GATE(2,7,0x61,0xAA)
#undef GATE

    // ---- <Z_0>: sign = parity(amp & 0x4C) = parity(k&4) ^ parity(g&0xC) ----
    float tp = 0.f, tn = 0.f;
#pragma unroll
    for (int k = 0; k < 16; k++) {
        float m = fmaf(kr[k], kr[k], ki[k] * ki[k]);
        if ((k >> 2) & 1) tn += m; else tp += m;
    }
    float tt = tp - tn;
    bool pg = (__popc(g & 0x0C) & 1) != 0;
    float e = pg ? -tt : tt;
    // 16-lane row reduce
    e += dppx<1>(e);
    e += dppx<2>(e);
    e += dppx<4>(e);
    e += dppx<8>(e);

    // gather the 4 rows' e per lane (no LDS, no barrier)
    float eown = e;
    float ex16 = px16v(e, lane);
    float ex32 = px32v(e, lane);
    float ex48 = px32v(ex16, lane);
    bool s0b = (lane >> 4) & 1;
    bool s1b = (lane >> 5) & 1;
    float e0 = s1b ? (s0b ? ex48 : ex32) : (s0b ? ex16 : eown);
    float e1 = s1b ? (s0b ? ex32 : ex48) : (s0b ? eown : ex16);
    float e2 = s1b ? (s0b ? ex16 : eown) : (s0b ? ex48 : ex32);
    float e3 = s1b ? (s0b ? eown : ex16) : (s0b ? ex32 : ex48);

    // ---- decoder, wave-wide, weights loaded once for all 4 rows ----
    float a0c = 0.f, a1c = 0.f, a2c = 0.f, a3c = 0.f;
#pragma unroll
    for (int m = 0; m < 4; m++) {
        int j = lane + 64 * m;
        float w1v = dw1[j], bv = db1[j], w2v = dw2[j];
        a0c = fmaf(fmaxf(fmaf(e0, w1v, bv), 0.f), w2v, a0c);
        a1c = fmaf(fmaxf(fmaf(e1, w1v, bv), 0.f), w2v, a1c);
        a2c = fmaf(fmaxf(fmaf(e2, w1v, bv), 0.f), w2v, a2c);
        a3c = fmaf(fmaxf(fmaf(e3, w1v, bv), 0.f), w2v, a3c);
    }
    a0c = wred(a0c, lane);
    a1c = wred(a1c, lane);
    a2c = wred(a2c, lane);
    a3c = wred(a3c, lane);

    if (lane < 4) {
        float av = (lane == 0) ? a0c : (lane == 1) ? a1c : (lane == 2) ? a2c : a3c;
        int orow = rowbase + lane;
        if (orow < B)
            out[orow] = 1.f / (1.f + __expf(-(av + db2[0])));
    }
}

extern "C" void kernel_launch(void* const* d_in, const int* in_sizes, int n_in,
                              void* d_out, int out_size, void* d_ws, size_t ws_size,
                              hipStream_t stream) {
    const float* x   = (const float*)d_in[0];
    const float* w1  = (const float*)d_in[1];
    const float* b1  = (const float*)d_in[2];
    const float* w2  = (const float*)d_in[3];
    const float* b2  = (const float*)d_in[4];
    const float* qp  = (const float*)d_in[5];
    const float* dw1 = (const float*)d_in[6];
    const float* db1 = (const float*)d_in[7];
    const float* dw2 = (const float*)d_in[8];
    const float* db2 = (const float*)d_in[9];
    float* out = (float*)d_out;

    const int B = in_sizes[0] / FDIM;
    const int grid = (B + ROWS_PER_BLOCK - 1) / ROWS_PER_BLOCK;
    hqcl_kernel<<<grid, THREADS, 0, stream>>>(x, w1, b1, w2, b2, qp, dw1, db1, dw2, db2, out, B);
}

// Round 12
// 49.473 us; speedup vs baseline: 1.0910x; 1.0910x over previous
//
#include <hip/hip_runtime.h>
#include <math.h>

#define NQ 8
#define DEPTH 3
#define FDIM 16
#define HDIM 256
#define WAVES_PER_BLOCK 4
#define THREADS (WAVES_PER_BLOCK * 64)
#define ROWS_PER_BLOCK (WAVES_PER_BLOCK * 2)   // 2 rows per wave
#define NGATE (NQ * DEPTH)        // 24

// ---------------- DPP helpers ----------------
template<int CTRL>
__device__ __forceinline__ float dpp1(float v) {
    return __int_as_float(__builtin_amdgcn_update_dpp(
        0, __float_as_int(v), CTRL, 0xF, 0xF, true));
}

// xor-mask shuffle within 16-lane rows, any 4-bit mask (R4-validated table)
template<int M4>
__device__ __forceinline__ float dppx(float v) {
    if constexpr (M4 == 0)  return v;
    else if constexpr (M4 == 1)  return dpp1<0xB1>(v);
    else if constexpr (M4 == 2)  return dpp1<0x4E>(v);
    else if constexpr (M4 == 3)  return dpp1<0x1B>(v);
    else if constexpr (M4 == 4)  return dpp1<0x1B>(dpp1<0x141>(v));
    else if constexpr (M4 == 5)  return dpp1<0x4E>(dpp1<0x141>(v));
    else if constexpr (M4 == 6)  return dpp1<0xB1>(dpp1<0x141>(v));
    else if constexpr (M4 == 7)  return dpp1<0x141>(v);
    else if constexpr (M4 == 8)  return dpp1<0x128>(v);
    else if constexpr (M4 == 9)  return dpp1<0xB1>(dpp1<0x128>(v));
    else if constexpr (M4 == 10) return dpp1<0x4E>(dpp1<0x128>(v));
    else if constexpr (M4 == 11) return dpp1<0x1B>(dpp1<0x128>(v));
    else if constexpr (M4 == 12) return dpp1<0x1B>(dpp1<0x140>(v));
    else if constexpr (M4 == 13) return dpp1<0x4E>(dpp1<0x140>(v));
    else if constexpr (M4 == 14) return dpp1<0xB1>(dpp1<0x140>(v));
    else                         return dpp1<0x140>(v);
}

// value from lane^16 / lane^32 (R3-verified select form)
__device__ __forceinline__ float px16v(float v, int lane) {
#if __has_builtin(__builtin_amdgcn_permlane16_swap)
    auto r = __builtin_amdgcn_permlane16_swap(__float_as_int(v), __float_as_int(v), false, false);
    return __int_as_float((lane & 16) ? r[0] : r[1]);
#else
    return __shfl_xor(v, 16, 64);
#endif
}
__device__ __forceinline__ float px32v(float v, int lane) {
#if __has_builtin(__builtin_amdgcn_permlane32_swap)
    auto r = __builtin_amdgcn_permlane32_swap(__float_as_int(v), __float_as_int(v), false, false);
    return __int_as_float((lane & 32) ? r[0] : r[1]);
#else
    return __shfl_xor(v, 32, 64);
#endif
}

// general 5-bit lane xor shuffle, all VALU
template<int ML>
__device__ __forceinline__ float shuf5(float v, int lane) {
    float r = v;
    if constexpr ((ML & 15) != 0) r = dppx<ML & 15>(r);
    if constexpr ((ML & 16) != 0) r = px16v(r, lane);
    return r;
}

// full 64-lane sum (validated): no-select permlane trick for 16/32
__device__ __forceinline__ float wred(float v, int lane) {
    v += dppx<1>(v);
    v += dppx<2>(v);
    v += dppx<4>(v);
    v += dppx<8>(v);
#if __has_builtin(__builtin_amdgcn_permlane16_swap)
    {
        auto r = __builtin_amdgcn_permlane16_swap(__float_as_int(v), __float_as_int(v), false, false);
        v = __int_as_float(r[0]) + __int_as_float(r[1]);
    }
#else
    v += __shfl_xor(v, 16, 64);
#endif
#if __has_builtin(__builtin_amdgcn_permlane32_swap)
    {
        auto r = __builtin_amdgcn_permlane32_swap(__float_as_int(v), __float_as_int(v), false, false);
        v = __int_as_float(r[0]) + __int_as_float(r[1]);
    }
#else
    v += __shfl_xor(v, 32, 64);
#endif
    return v;
}

__device__ __forceinline__ float fast_tanh(float y) {
    float ex = __expf(2.f * y);
    return 1.f - 2.f * __builtin_amdgcn_rcpf(ex + 1.f);
}

// ---------------- merged RZ*RY gate, 32-lane-row layout ----------------
// amp = (k<<5)|(lane&31), row = lane>>5. Reg mask MK = M>>5 (free relabel),
// lane mask ML = M&31 (DPP + permlane16). Algebra = R10's verified gate_m:
// amp' = L*amp + P*amp(x^M); L = a0 + i*eta*a1, P = eta*b0 - i*b1,
// eta = parity(amp & R) ? +1 : -1. Per-k signs are constexpr -> free neg mods.
template<int M, int R>
__device__ __forceinline__ void gate32(float (&kr)[8], float (&ki)[8],
                                       float a0, float a1, float b0, float b1,
                                       int lane) {
    constexpr int MK = (M >> 5) & 7, ML = M & 31;
    constexpr int RK = (R >> 5) & 7, RL = R & 31;
    bool p0;
    if constexpr (RL == 0)                 p0 = false;
    else if constexpr ((RL & (RL-1)) == 0) p0 = (lane & RL) != 0;
    else                                   p0 = (__popc(lane & RL) & 1) != 0;
    float ea1 = p0 ? a1 : -a1;
    float eb0 = p0 ? b0 : -b0;

    float pr[8], pi[8];
#pragma unroll
    for (int k = 0; k < 8; k++) {
        pr[k] = shuf5<ML>(kr[k ^ MK], lane);
        pi[k] = shuf5<ML>(ki[k ^ MK], lane);
    }
#pragma unroll
    for (int k = 0; k < 8; k++) {
        const bool f = (__builtin_popcount(k & RK) & 1) != 0;   // constexpr
        float za1 = f ? -ea1 : ea1;
        float zb0 = f ? -eb0 : eb0;
        float lr = fmaf(-za1, ki[k], a0 * kr[k]);
        float li = fmaf( za1, kr[k], a0 * ki[k]);
        kr[k] = fmaf( b1, pi[k], fmaf(zb0, pr[k], lr));
        ki[k] = fmaf(-b1, pr[k], fmaf(zb0, pi[k], li));
    }
}

__global__ __launch_bounds__(THREADS, 4) void hqcl_kernel(
    const float* __restrict__ x,     // (B,16)
    const float* __restrict__ w1,    // (256,16)
    const float* __restrict__ b1,    // (256)
    const float* __restrict__ w2,    // (8,256)
    const float* __restrict__ b2,    // (8)
    const float* __restrict__ qp,    // (48)
    const float* __restrict__ dw1,   // (256,1)
    const float* __restrict__ db1,   // (256)
    const float* __restrict__ dw2,   // (1,256)
    const float* __restrict__ db2,   // (1)
    float* __restrict__ out, int B)
{
    __shared__ float4 sG4[NGATE];    // (a0,a1,b0,b1) per gate

    const int t = threadIdx.x;
    if (t < NGATE) {
        float cz, sz, cy, sy;
        __sincosf(qp[2 * t] * 0.5f,     &sz, &cz);
        __sincosf(qp[2 * t + 1] * 0.5f, &sy, &cy);
        sG4[t] = make_float4(cz * cy, sz * cy, cz * sy, sz * sy);
    }
    __syncthreads();

    const int lane = t & 63;
    const int row0 = blockIdx.x * ROWS_PER_BLOCK + (t >> 6) * 2;
    if (row0 >= B) return;
    const int rowB = (row0 + 1 < B) ? row0 + 1 : row0;

    // ======== phase 1: encoder + angles, R10-proven 2-row structure ========
    const float4* xA = (const float4*)(x + row0 * FDIM);
    const float4* xB = (const float4*)(x + rowB * FDIM);
    float4 xa0 = xA[0], xa1 = xA[1], xa2 = xA[2], xa3 = xA[3];
    float4 xb0 = xB[0], xb1 = xB[1], xb2 = xB[2], xb3 = xB[3];

    float hA[4], hB[4];
#pragma unroll
    for (int m = 0; m < 4; m++) {
        int j = lane + 64 * m;
        const float4* wp = (const float4*)(w1 + j * FDIM);
        float4 wa = wp[0], wb = wp[1], wc = wp[2], wd = wp[3];
        float bv = b1[j];
        float aA = bv, aB = bv;
        aA = fmaf(xa0.x, wa.x, aA); aA = fmaf(xa0.y, wa.y, aA);
        aA = fmaf(xa0.z, wa.z, aA); aA = fmaf(xa0.w, wa.w, aA);
        aA = fmaf(xa1.x, wb.x, aA); aA = fmaf(xa1.y, wb.y, aA);
        aA = fmaf(xa1.z, wb.z, aA); aA = fmaf(xa1.w, wb.w, aA);
        aA = fmaf(xa2.x, wc.x, aA); aA = fmaf(xa2.y, wc.y, aA);
        aA = fmaf(xa2.z, wc.z, aA); aA = fmaf(xa2.w, wc.w, aA);
        aA = fmaf(xa3.x, wd.x, aA); aA = fmaf(xa3.y, wd.y, aA);
        aA = fmaf(xa3.z, wd.z, aA); aA = fmaf(xa3.w, wd.w, aA);
        aB = fmaf(xb0.x, wa.x, aB); aB = fmaf(xb0.y, wa.y, aB);
        aB = fmaf(xb0.z, wa.z, aB); aB = fmaf(xb0.w, wa.w, aB);
        aB = fmaf(xb1.x, wb.x, aB); aB = fmaf(xb1.y, wb.y, aB);
        aB = fmaf(xb1.z, wb.z, aB); aB = fmaf(xb1.w, wb.w, aB);
        aB = fmaf(xb2.x, wc.x, aB); aB = fmaf(xb2.y, wc.y, aB);
        aB = fmaf(xb2.z, wc.z, aB); aB = fmaf(xb2.w, wc.w, aB);
        aB = fmaf(xb3.x, wd.x, aB); aB = fmaf(xb3.y, wd.y, aB);
        aB = fmaf(xb3.z, wd.z, aB); aB = fmaf(xb3.w, wd.w, aB);
        hA[m] = fmaxf(aA, 0.f);
        hB[m] = fmaxf(aB, 0.f);
    }

    // angles: u = tanh(.)/4 revolutions; every lane holds BOTH rows' (c,s),
    // so phase 2 just row-selects: cq/sq for MY row (row = lane>>5).
    // q0,q1,q2 -> k bits 2,1,0 (kept); q3..q7 -> lane bits 4..0 (folded).
    float c0r, s0r, c1r, s1r, c2r, s2r;
    float plg = 1.f;
#pragma unroll
    for (int q = 0; q < NQ; q++) {
        float aA = 0.f, aB = 0.f;
#pragma unroll
        for (int m = 0; m < 4; m++) {
            float wv = w2[q * HDIM + lane + 64 * m];
            aA = fmaf(hA[m], wv, aA);
            aB = fmaf(hB[m], wv, aB);
        }
        aA = wred(aA, lane);
        aB = wred(aB, lane);
        float bq = b2[q];
        float uA = 0.25f * fast_tanh(aA + bq);
        float uB = 0.25f * fast_tanh(aB + bq);
        float svA, cvA, svB, cvB;
        asm("v_sin_f32 %0, %1" : "=v"(svA) : "v"(uA));
        asm("v_cos_f32 %0, %1" : "=v"(cvA) : "v"(uA));
        asm("v_sin_f32 %0, %1" : "=v"(svB) : "v"(uB));
        asm("v_cos_f32 %0, %1" : "=v"(cvB) : "v"(uB));
        float cq = (lane & 32) ? cvB : cvA;
        float sq = (lane & 32) ? svB : svA;
        if (q == 0)      { c0r = cq; s0r = sq; }
        else if (q == 1) { c1r = cq; s1r = sq; }
        else if (q == 2) { c2r = cq; s2r = sq; }
        else             { plg *= ((lane >> (7 - q)) & 1) ? sq : cq; }
    }

    // ======== phase 2: circuit, 32 lanes/row, 8 complex regs/lane, DS-free ====
    float pq[4];
    pq[0] = plg * c0r * c1r;
    pq[1] = plg * c0r * s1r;
    pq[2] = plg * s0r * c1r;
    pq[3] = plg * s0r * s1r;
    float kr[8], ki[8];
#pragma unroll
    for (int k = 0; k < 8; k++) {
        kr[k] = pq[k >> 1] * ((k & 1) ? s2r : c2r);
        ki[k] = 0.f;
    }

    // masks/parities: identical verified 8-bit constants; split k=bits7:5, lane=4:0
#define GATE(L, Q, MM, RR) { float4 g4 = sG4[(L)*8 + (Q)]; \
        gate32<MM, RR>(kr, ki, g4.x, g4.y, g4.z, g4.w, lane); }
    GATE(0,0,0x80,0x80) GATE(0,1,0x40,0x40) GATE(0,2,0x20,0x20) GATE(0,3,0x10,0x10)
    GATE(0,4,0x08,0x08) GATE(0,5,0x04,0x04) GATE(0,6,0x02,0x02) GATE(0,7,0x01,0x01)
    GATE(1,0,0xC0,0x7F) GATE(1,1,0x60,0xC0) GATE(1,2,0x30,0xE0) GATE(1,3,0x18,0xF0)
    GATE(1,4,0x0C,0xF8) GATE(1,5,0x06,0xFC) GATE(1,6,0x03,0xFE) GATE(1,7,0xC1,0xFF)
    GATE(2,0,0xA0,0xD5) GATE(2,1,0x50,0xBF) GATE(2,2,0x28,0x5F) GATE(2,3,0x14,0xAF)
    GATE(2,4,0x0A,0x57) GATE(2,5,0x05,0xAB) GATE(2,6,0xC2,0x55) GATE(2,7,0x61,0xAA)
#undef GATE

    // ---- <Z_0>: sign = parity(amp & 0x4C) = parity(k&2) ^ parity(lane&0xC) ----
    float tp = 0.f, tn = 0.f;
#pragma unroll
    for (int k = 0; k < 8; k++) {
        float m = fmaf(kr[k], kr[k], ki[k] * ki[k]);
        if ((k >> 1) & 1) tn += m; else tp += m;
    }
    float tt = tp - tn;
    bool pg = (__popc(lane & 0x0C) & 1) != 0;
    float e = pg ? -tt : tt;
    // 32-lane row reduce (stages 1..16; permlane16 no-select trick stays in-half)
    e += dppx<1>(e);
    e += dppx<2>(e);
    e += dppx<4>(e);
    e += dppx<8>(e);
#if __has_builtin(__builtin_amdgcn_permlane16_swap)
    {
        auto r = __builtin_amdgcn_permlane16_swap(__float_as_int(e), __float_as_int(e), false, false);
        e = __int_as_float(r[0]) + __int_as_float(r[1]);
    }
#else
    e += __shfl_xor(e, 16, 64);
#endif
    // recover (eA, eB) in every lane
    float eo = px32v(e, lane);
    float eA = (lane & 32) ? eo : e;
    float eB = (lane & 32) ? e : eo;

    // ---- decoder (R10-proven, weights shared across rows) ----
    float accA = 0.f, accB = 0.f;
#pragma unroll
    for (int m = 0; m < 4; m++) {
        int j = lane + 64 * m;
        float w1v = dw1[j], bv = db1[j], w2v = dw2[j];
        float dA = fmaxf(fmaf(eA, w1v, bv), 0.f);
        float dB = fmaxf(fmaf(eB, w1v, bv), 0.f);
        accA = fmaf(dA, w2v, accA);
        accB = fmaf(dB, w2v, accB);
    }
    accA = wred(accA, lane);
    accB = wred(accB, lane);
    if (lane == 0) {
        float bb = db2[0];
        out[row0] = 1.f / (1.f + __expf(-(accA + bb)));
        if (row0 + 1 < B)
            out[row0 + 1] = 1.f / (1.f + __expf(-(accB + bb)));
    }
}

extern "C" void kernel_launch(void* const* d_in, const int* in_sizes, int n_in,
                              void* d_out, int out_size, void* d_ws, size_t ws_size,
                              hipStream_t stream) {
    const float* x   = (const float*)d_in[0];
    const float* w1  = (const float*)d_in[1];
    const float* b1  = (const float*)d_in[2];
    const float* w2  = (const float*)d_in[3];
    const float* b2  = (const float*)d_in[4];
    const float* qp  = (const float*)d_in[5];
    const float* dw1 = (const float*)d_in[6];
    const float* db1 = (const float*)d_in[7];
    const float* dw2 = (const float*)d_in[8];
    const float* db2 = (const float*)d_in[9];
    float* out = (float*)d_out;

    const int B = in_sizes[0] / FDIM;
    const int grid = (B + ROWS_PER_BLOCK - 1) / ROWS_PER_BLOCK;
    hqcl_kernel<<<grid, THREADS, 0, stream>>>(x, w1, b1, w2, b2, qp, dw1, db1, dw2, db2, out, B);
}

// Round 13
// 40.170 us; speedup vs baseline: 1.3437x; 1.2316x over previous
//
#include <hip/hip_runtime.h>
#include <math.h>

#define NQ 8
#define DEPTH 3
#define FDIM 16
#define HDIM 256
#define WAVES_PER_BLOCK 4
#define THREADS (WAVES_PER_BLOCK * 64)
#define NGATE (NQ * DEPTH)        // 24 (RZ,RY) pairs

// ---------------- cross-lane xor shuffles ----------------
template<int CTRL>
__device__ __forceinline__ float dpp1(float v) {
    return __int_as_float(__builtin_amdgcn_update_dpp(
        0, __float_as_int(v), CTRL, 0xF, 0xF, true));
}

// full 4-bit xor table via DPP (R4-validated); single-DPP masks: 1,2,3,7,8,15
template<int M4>
__device__ __forceinline__ float dppx(float v) {
    if constexpr (M4 == 0)  return v;
    else if constexpr (M4 == 1)  return dpp1<0xB1>(v);
    else if constexpr (M4 == 2)  return dpp1<0x4E>(v);
    else if constexpr (M4 == 3)  return dpp1<0x1B>(v);
    else if constexpr (M4 == 4)  return dpp1<0x1B>(dpp1<0x141>(v));
    else if constexpr (M4 == 5)  return dpp1<0x4E>(dpp1<0x141>(v));
    else if constexpr (M4 == 6)  return dpp1<0xB1>(dpp1<0x141>(v));
    else if constexpr (M4 == 7)  return dpp1<0x141>(v);
    else if constexpr (M4 == 8)  return dpp1<0x128>(v);
    else if constexpr (M4 == 9)  return dpp1<0xB1>(dpp1<0x128>(v));
    else if constexpr (M4 == 10) return dpp1<0x4E>(dpp1<0x128>(v));
    else if constexpr (M4 == 11) return dpp1<0x1B>(dpp1<0x128>(v));
    else if constexpr (M4 == 12) return dpp1<0x1B>(dpp1<0x140>(v));
    else if constexpr (M4 == 13) return dpp1<0x4E>(dpp1<0x140>(v));
    else if constexpr (M4 == 14) return dpp1<0xB1>(dpp1<0x140>(v));
    else                         return dpp1<0x140>(v);
}

// gate shuffle routing (pipe-balanced):
//  - single-DPP masks {1,2,3,7,8,15}: VALU (1 inst)
//  - all other masks < 32: ds_swizzle (1 DS op, 0 VALU)
//  - masks >= 32: ds_bpermute
template<int ML>
__device__ __forceinline__ float shuf(float v, int lane) {
    if constexpr (ML == 0) {
        return v;
    } else if constexpr (ML >= 32) {
        int addr = (lane ^ ML) << 2;
        return __int_as_float(__builtin_amdgcn_ds_bpermute(addr, __float_as_int(v)));
    } else if constexpr (ML == 1 || ML == 2 || ML == 3 || ML == 7 || ML == 8 || ML == 15) {
        return dppx<ML>(v);
    } else {
        return __int_as_float(__builtin_amdgcn_ds_swizzle(
            __float_as_int(v), (ML << 10) | 0x1F));   // BitMode xor=ML
    }
}

// full 64-lane sum, latency-optimal (all-VALU; validated R5+)
__device__ __forceinline__ float wred(float v, int lane) {
    v += dppx<1>(v);
    v += dppx<2>(v);
    v += dppx<4>(v);
    v += dppx<8>(v);
#if __has_builtin(__builtin_amdgcn_permlane16_swap)
    {
        auto r = __builtin_amdgcn_permlane16_swap(__float_as_int(v), __float_as_int(v), false, false);
        v = __int_as_float(r[0]) + __int_as_float(r[1]);
    }
#else
    v += __shfl_xor(v, 16, 64);
#endif
#if __has_builtin(__builtin_amdgcn_permlane32_swap)
    {
        auto r = __builtin_amdgcn_permlane32_swap(__float_as_int(v), __float_as_int(v), false, false);
        v = __int_as_float(r[0]) + __int_as_float(r[1]);
    }
#else
    v += __shfl_xor(v, 32, 64);
#endif
    return v;
}

__device__ __forceinline__ float fast_tanh(float y) {
    float ex = __expf(2.f * y);                       // inf for large y -> t=1
    return 1.f - 2.f * __builtin_amdgcn_rcpf(ex + 1.f);
}

// ---------------- merged RZ*RY gate (R10-verified algebra), one row ----------------
// amp' (x) = L(x)*amp(x) + P(x)*amp(x^M);
//   L = a0 + i*eta*a1,  P = eta*b0 - i*b1   (a0=cy*cz, a1=cy*sz, b0=sy*cz, b1=sy*sz)
//   eta(x) = +1 iff parity(x & R); cross term sign uniform since parity(M&R)==1.
// Shuffles read the PRE-gate state -> all 8 DS/DPP ops issue first, and the
// 16 local FMAs execute under the DS round-trip (vs R5's RZ->shuffle->RY serial).
template<int M, int R>
__device__ __forceinline__ void gate_m(float (&sr)[4], float (&si)[4],
                                       float a0, float a1, float b0, float b1,
                                       int lane) {
    constexpr int ML = M & 63, MH = (M >> 6) & 3;
    constexpr int RL = R & 63, RH = (R >> 6) & 3;
    bool p0;
    if constexpr (RL == 0)                 p0 = false;
    else if constexpr ((RL & (RL-1)) == 0) p0 = (lane & RL) != 0;
    else                                   p0 = (__popc(lane & RL) & 1) != 0;

    // partner snapshot of pre-gate state
    float pr[4], pi[4];
#pragma unroll
    for (int hi = 0; hi < 4; hi++) {
        pr[hi] = shuf<ML>(sr[hi ^ MH], lane);
        pi[hi] = shuf<ML>(si[hi ^ MH], lane);
    }

    float ea1 = p0 ? a1 : -a1;
    float eb0 = p0 ? b0 : -b0;

#pragma unroll
    for (int hi = 0; hi < 4; hi++) {
        const bool f = (__builtin_popcount(hi & RH) & 1) != 0;   // constexpr fold
        float za1 = f ? -ea1 : ea1;    // eta*a1
        float zb0 = f ? -eb0 : eb0;    // eta*b0
        float lr = fmaf(-za1, si[hi], a0 * sr[hi]);
        float li = fmaf( za1, sr[hi], a0 * si[hi]);
        sr[hi] = fmaf( b1, pi[hi], fmaf(zb0, pr[hi], lr));
        si[hi] = fmaf(-b1, pr[hi], fmaf(zb0, pi[hi], li));
    }
}

__global__ __launch_bounds__(THREADS) void hqcl_kernel(
    const float* __restrict__ x,     // (B,16)
    const float* __restrict__ w1,    // (256,16)
    const float* __restrict__ b1,    // (256)
    const float* __restrict__ w2,    // (8,256)
    const float* __restrict__ b2,    // (8)
    const float* __restrict__ qp,    // (48)
    const float* __restrict__ dw1,   // (256,1)
    const float* __restrict__ db1,   // (256)
    const float* __restrict__ dw2,   // (1,256)
    const float* __restrict__ db2,   // (1)
    float* __restrict__ out, int B)
{
    __shared__ float4 sG4[NGATE];    // (a0,a1,b0,b1) products per gate

    const int t = threadIdx.x;
    if (t < NGATE) {
        float cz, sz, cy, sy;
        __sincosf(qp[2 * t] * 0.5f,     &sz, &cz);
        __sincosf(qp[2 * t + 1] * 0.5f, &sy, &cy);
        sG4[t] = make_float4(cz * cy, sz * cy, cz * sy, sz * sy);
    }
    __syncthreads();

    const int lane = t & 63;
    const int row  = blockIdx.x * WAVES_PER_BLOCK + (t >> 6);
    if (row >= B) return;

    // ---- encoder: h = relu(x @ W1^T + b1)  (R5-proven full-hoist form) ----
    const float4* xp = (const float4*)(x + row * FDIM);
    float4 x0 = xp[0], x1 = xp[1], x2 = xp[2], x3 = xp[3];

    float hreg[4];
#pragma unroll
    for (int m = 0; m < 4; m++) {
        int j = lane + 64 * m;
        const float4* wp = (const float4*)(w1 + j * FDIM);
        float4 wa = wp[0], wb = wp[1], wc = wp[2], wd = wp[3];
        float acc = b1[j];
        acc = fmaf(x0.x, wa.x, acc); acc = fmaf(x0.y, wa.y, acc);
        acc = fmaf(x0.z, wa.z, acc); acc = fmaf(x0.w, wa.w, acc);
        acc = fmaf(x1.x, wb.x, acc); acc = fmaf(x1.y, wb.y, acc);
        acc = fmaf(x1.z, wb.z, acc); acc = fmaf(x1.w, wb.w, acc);
        acc = fmaf(x2.x, wc.x, acc); acc = fmaf(x2.y, wc.y, acc);
        acc = fmaf(x2.z, wc.z, acc); acc = fmaf(x2.w, wc.w, acc);
        acc = fmaf(x3.x, wd.x, acc); acc = fmaf(x3.y, wd.y, acc);
        acc = fmaf(x3.z, wd.z, acc); acc = fmaf(x3.w, wd.w, acc);
        hreg[m] = fmaxf(acc, 0.f);
    }

    // ---- angles = tanh(h @ W2^T + b2) * pi ----
    // angle/2 = tanh*pi/2 rad = tanh/4 revolutions -> native v_sin/v_cos range
    float c0[NQ], s0[NQ];
#pragma unroll
    for (int q = 0; q < NQ; q++) {
        float a = 0.f;
#pragma unroll
        for (int m = 0; m < 4; m++)
            a = fmaf(hreg[m], w2[q * HDIM + lane + 64 * m], a);
        a = wred(a, lane);
        float u = 0.25f * fast_tanh(a + b2[q]);
        float sv, cv;
        asm("v_sin_f32 %0, %1" : "=v"(sv) : "v"(u));
        asm("v_cos_f32 %0, %1" : "=v"(cv) : "v"(u));
        s0[q] = sv; c0[q] = cv;
    }

    // ---- initial 8 RYs on |0..0> -> product state (amp x = hi*64 + lane) ----
    float pl = 1.f;
#pragma unroll
    for (int b = 0; b < 6; b++) {
        int q = 7 - b;
        pl *= ((lane >> b) & 1) ? s0[q] : c0[q];
    }
    float sr[4], si[4];
    sr[0] = pl * c0[1] * c0[0];
    sr[1] = pl * s0[1] * c0[0];
    sr[2] = pl * c0[1] * s0[0];
    sr[3] = pl * s0[1] * s0[0];
#pragma unroll
    for (int hi = 0; hi < 4; hi++) si[hi] = 0.f;

    // ---- circuit: CX chains folded into per-layer masks (GF(2) relabeling) ----
    // A cols: C1 03 06 0C 18 30 60 C0 ; A^2 cols: 61 C2 05 0A 14 28 50 A0
    // A^-1 rows: FF FE FC F8 F0 E0 C0 7F ; A^-2 rows: AA 55 AB 57 AF 5F BF D5
#define GATE(L, Q, MM, RR) { float4 g4 = sG4[(L)*8 + (Q)]; \
        gate_m<MM, RR>(sr, si, g4.x, g4.y, g4.z, g4.w, lane); }
    // layer 0 (identity labeling)
    GATE(0,0,0x80,0x80) GATE(0,1,0x40,0x40) GATE(0,2,0x20,0x20) GATE(0,3,0x10,0x10)
    GATE(0,4,0x08,0x08) GATE(0,5,0x04,0x04) GATE(0,6,0x02,0x02) GATE(0,7,0x01,0x01)
    // layer 1 (masks = cols of A, parities = rows of A^-1)
    GATE(1,0,0xC0,0x7F) GATE(1,1,0x60,0xC0) GATE(1,2,0x30,0xE0) GATE(1,3,0x18,0xF0)
    GATE(1,4,0x0C,0xF8) GATE(1,5,0x06,0xFC) GATE(1,6,0x03,0xFE) GATE(1,7,0xC1,0xFF)
    // layer 2 (masks = cols of A^2, parities = rows of A^-2)
    GATE(2,0,0xA0,0xD5) GATE(2,1,0x50,0xBF) GATE(2,2,0x28,0x5F) GATE(2,3,0x14,0xAF)
    GATE(2,4,0x0A,0x57) GATE(2,5,0x05,0xAB) GATE(2,6,0xC2,0x55) GATE(2,7,0x61,0xAA)
#undef GATE

    // ---- <Z_0> with final labeling: sign = parity(x & 0x4C) (row7 of A^-3) ----
    float m0 = sr[0]*sr[0] + si[0]*si[0] + sr[2]*sr[2] + si[2]*si[2]; // hi&1==0
    float m1 = sr[1]*sr[1] + si[1]*si[1] + sr[3]*sr[3] + si[3]*si[3]; // hi&1==1
    bool pb = (__popc(lane & 0x0C) & 1) != 0;
    float e = pb ? (m1 - m0) : (m0 - m1);
    e = wred(e, lane);

    // ---- decoder ----
    float acc = 0.f;
#pragma unroll
    for (int m = 0; m < 4; m++) {
        int j = lane + 64 * m;
        float d = fmaxf(fmaf(e, dw1[j], db1[j]), 0.f);
        acc = fmaf(d, dw2[j], acc);
    }
    acc = wred(acc, lane);
    if (lane == 0) out[row] = 1.f / (1.f + __expf(-(acc + db2[0])));
}

extern "C" void kernel_launch(void* const* d_in, const int* in_sizes, int n_in,
                              void* d_out, int out_size, void* d_ws, size_t ws_size,
                              hipStream_t stream) {
    const float* x   = (const float*)d_in[0];
    const float* w1  = (const float*)d_in[1];
    const float* b1  = (const float*)d_in[2];
    const float* w2  = (const float*)d_in[3];
    const float* b2  = (const float*)d_in[4];
    const float* qp  = (const float*)d_in[5];
    const float* dw1 = (const float*)d_in[6];
    const float* db1 = (const float*)d_in[7];
    const float* dw2 = (const float*)d_in[8];
    const float* db2 = (const float*)d_in[9];
    float* out = (float*)d_out;

    const int B = in_sizes[0] / FDIM;
    const int grid = (B + WAVES_PER_BLOCK - 1) / WAVES_PER_BLOCK;
    hqcl_kernel<<<grid, THREADS, 0, stream>>>(x, w1, b1, w2, b2, qp, dw1, db1, dw2, db2, out, B);
}

// Round 14
// 39.367 us; speedup vs baseline: 1.3711x; 1.0204x over previous
//
#include <hip/hip_runtime.h>
#include <math.h>

#define NQ 8
#define DEPTH 3
#define FDIM 16
#define HDIM 256
#define WAVES_PER_BLOCK 4
#define THREADS (WAVES_PER_BLOCK * 64)
#define NGATE (NQ * DEPTH)        // 24 (RZ,RY) pairs

// ---------------- cross-lane xor shuffles ----------------
template<int CTRL>
__device__ __forceinline__ float dpp1(float v) {
    return __int_as_float(__builtin_amdgcn_update_dpp(
        0, __float_as_int(v), CTRL, 0xF, 0xF, true));
}

// single-DPP xor masks used by wred (VALU, lowest latency)
template<int M4>
__device__ __forceinline__ float shuf4(float v) {
    if constexpr (M4 == 1)  return dpp1<0xB1>(v);   // quad_perm xor1
    else if constexpr (M4 == 2)  return dpp1<0x4E>(v);   // quad_perm xor2
    else if constexpr (M4 == 4)  return dpp1<0x1B>(dpp1<0x141>(v)); // xor3 o xor7
    else if constexpr (M4 == 8)  return dpp1<0x128>(v);  // row_ror:8 == xor8
    else return v;
}

// general 6-bit xor shuffle on the LDS pipe (0 VALU slots):
// ds_swizzle BitMode for masks 1..31, ds_bpermute for masks with bit5 set.
template<int ML>
__device__ __forceinline__ float shuf(float v, int lane) {
    if constexpr (ML == 0) {
        return v;
    } else if constexpr (ML >= 32) {
        int addr = (lane ^ ML) << 2;   // CSE'd across the 8 uses per gate
        return __int_as_float(__builtin_amdgcn_ds_bpermute(addr, __float_as_int(v)));
    } else {
        return __int_as_float(__builtin_amdgcn_ds_swizzle(
            __float_as_int(v), (ML << 10) | 0x1F));   // xor=ML, and=0x1F
    }
}

// full 64-lane sum, all lanes receive the total.
// permlane*_swap trick: r[0]+r[1] == v + v[lane^K] for every lane (no select).
__device__ __forceinline__ float wred(float v, int lane) {
    v += shuf4<1>(v);
    v += shuf4<2>(v);
    v += shuf4<4>(v);
    v += shuf4<8>(v);
#if __has_builtin(__builtin_amdgcn_permlane16_swap)
    {
        auto r = __builtin_amdgcn_permlane16_swap(__float_as_int(v), __float_as_int(v), false, false);
        v = __int_as_float(r[0]) + __int_as_float(r[1]);
    }
#else
    v += __shfl_xor(v, 16, 64);
#endif
#if __has_builtin(__builtin_amdgcn_permlane32_swap)
    {
        auto r = __builtin_amdgcn_permlane32_swap(__float_as_int(v), __float_as_int(v), false, false);
        v = __int_as_float(r[0]) + __int_as_float(r[1]);
    }
#else
    v += __shfl_xor(v, 32, 64);
#endif
    return v;
}

__device__ __forceinline__ float fast_tanh(float y) {
    float ex = __expf(2.f * y);                       // inf for large y -> t=1
    return 1.f - 2.f * __builtin_amdgcn_rcpf(ex + 1.f);
}

// ---------------- relabeled gate ----------------
// Physical storage never permuted. Layer-l gates use pair-mask M = A^l*e_b and
// parity row R = row_b(A^{-l}), both 8-bit compile-time constants over
// x = (hi<<6)|lane.  RZ: amp *= (cz + i*sgz), sgz = p? sz : -sz.
// RY: amp = cy*amp + sgy*partner, partner at x ^ M, sgy = p? sy : -sy.
template<int M, int R>
__device__ __forceinline__ void gate2(float (&sr)[4], float (&si)[4],
                                      float cz, float szv, float cy, float sy,
                                      int lane) {
    constexpr int ML = M & 63, MH = (M >> 6) & 3;
    constexpr int RL = R & 63, RH = (R >> 6) & 3;
    bool p0;
    if constexpr (RL == 0)                 p0 = false;
    else if constexpr ((RL & (RL-1)) == 0) p0 = (lane & RL) != 0;
    else                                   p0 = (__popc(lane & RL) & 1) != 0;
    float sgz = p0 ? szv : -szv;
    float sgy = p0 ? sy  : -sy;
    // RZ (diagonal phase)
#pragma unroll
    for (int hi = 0; hi < 4; hi++) {
        const bool f = (__builtin_popcount(hi & RH) & 1) != 0;   // folds per-hi
        float z = f ? -sgz : sgz;
        float nr = fmaf(sr[hi], cz, -(si[hi] * z));
        float ni = fmaf(si[hi], cz,  (sr[hi] * z));
        sr[hi] = nr; si[hi] = ni;
    }
    // RY partners from post-RZ values
    float pr[4], pi[4];
#pragma unroll
    for (int hi = 0; hi < 4; hi++) {
        pr[hi] = shuf<ML>(sr[hi ^ MH], lane);
        pi[hi] = shuf<ML>(si[hi ^ MH], lane);
    }
#pragma unroll
    for (int hi = 0; hi < 4; hi++) {
        const bool f = (__builtin_popcount(hi & RH) & 1) != 0;
        float yv = f ? -sgy : sgy;
        sr[hi] = fmaf(yv, pr[hi], cy * sr[hi]);
        si[hi] = fmaf(yv, pi[hi], cy * si[hi]);
    }
}

__global__ __launch_bounds__(THREADS) void hqcl_kernel(
    const float* __restrict__ x,     // (B,16)
    const float* __restrict__ w1,    // (256,16)
    const float* __restrict__ b1,    // (256)
    const float* __restrict__ w2,    // (8,256)
    const float* __restrict__ b2,    // (8)
    const float* __restrict__ qp,    // (48)
    const float* __restrict__ dw1,   // (256,1)
    const float* __restrict__ db1,   // (256)
    const float* __restrict__ dw2,   // (1,256)
    const float* __restrict__ db2,   // (1)
    float* __restrict__ out, int B)
{
    __shared__ float4 sG4[NGATE];    // (cz,sz,cy,sy) per gate; gate g: qp[2g], qp[2g+1]

    const int t = threadIdx.x;
    if (t < 2 * NGATE) {
        float s, c;
        __sincosf(qp[t] * 0.5f, &s, &c);
        float* p = (float*)&sG4[t >> 1] + 2 * (t & 1);
        p[0] = c; p[1] = s;
    }
    __syncthreads();

    const int lane = t & 63;
    const int row  = blockIdx.x * WAVES_PER_BLOCK + (t >> 6);
    if (row >= B) return;

    // ---- encoder: h = relu(x @ W1^T + b1) ----
    const float4* xp = (const float4*)(x + row * FDIM);
    float4 x0 = xp[0], x1 = xp[1], x2 = xp[2], x3 = xp[3];

    float hreg[4];
#pragma unroll
    for (int m = 0; m < 4; m++) {
        int j = lane + 64 * m;
        const float4* wp = (const float4*)(w1 + j * FDIM);
        float4 wa = wp[0], wb = wp[1], wc = wp[2], wd = wp[3];
        float acc = b1[j];
        acc = fmaf(x0.x, wa.x, acc); acc = fmaf(x0.y, wa.y, acc);
        acc = fmaf(x0.z, wa.z, acc); acc = fmaf(x0.w, wa.w, acc);
        acc = fmaf(x1.x, wb.x, acc); acc = fmaf(x1.y, wb.y, acc);
        acc = fmaf(x1.z, wb.z, acc); acc = fmaf(x1.w, wb.w, acc);
        acc = fmaf(x2.x, wc.x, acc); acc = fmaf(x2.y, wc.y, acc);
        acc = fmaf(x2.z, wc.z, acc); acc = fmaf(x2.w, wc.w, acc);
        acc = fmaf(x3.x, wd.x, acc); acc = fmaf(x3.y, wd.y, acc);
        acc = fmaf(x3.z, wd.z, acc); acc = fmaf(x3.w, wd.w, acc);
        hreg[m] = fmaxf(acc, 0.f);
    }

    // ---- angles = tanh(h @ W2^T + b2) * pi ----
    // angle/2 = tanh*pi/2 rad = tanh/4 revolutions -> native v_sin/v_cos range
    float c0[NQ], s0[NQ];
#pragma unroll
    for (int q = 0; q < NQ; q++) {
        float a = 0.f;
#pragma unroll
        for (int m = 0; m < 4; m++)
            a = fmaf(hreg[m], w2[q * HDIM + lane + 64 * m], a);
        a = wred(a, lane);
        float u = 0.25f * fast_tanh(a + b2[q]);
        float sv, cv;
        asm("v_sin_f32 %0, %1" : "=v"(sv) : "v"(u));
        asm("v_cos_f32 %0, %1" : "=v"(cv) : "v"(u));
        s0[q] = sv; c0[q] = cv;
    }

    // ---- initial 8 RYs on |0..0> -> product state ----
    // amp index x = hi*64 + lane; qubit q <-> bit (7-q)
    float pl = 1.f;
#pragma unroll
    for (int b = 0; b < 6; b++) {
        int q = 7 - b;
        pl *= ((lane >> b) & 1) ? s0[q] : c0[q];
    }
    float sr[4], si[4];
    sr[0] = pl * c0[1] * c0[0];
    sr[1] = pl * s0[1] * c0[0];
    sr[2] = pl * c0[1] * s0[0];
    sr[3] = pl * s0[1] * s0[0];
#pragma unroll
    for (int hi = 0; hi < 4; hi++) si[hi] = 0.f;

    // ---- circuit: CX chains folded into per-layer masks (GF(2) relabeling) ----
    // A cols: C1 03 06 0C 18 30 60 C0 ; A^2 cols: 61 C2 05 0A 14 28 50 A0
    // A^-1 rows: FF FE FC F8 F0 E0 C0 7F ; A^-2 rows: AA 55 AB 57 AF 5F BF D5
#define GATE(L, Q, MM, RR) { float4 g4 = sG4[(L)*8 + (Q)]; \
        gate2<MM, RR>(sr, si, g4.x, g4.y, g4.z, g4.w, lane); }
    // layer 0 (identity labeling)
    GATE(0,0,0x80,0x80) GATE(0,1,0x40,0x40) GATE(0,2,0x20,0x20) GATE(0,3,0x10,0x10)
    GATE(0,4,0x08,0x08) GATE(0,5,0x04,0x04) GATE(0,6,0x02,0x02) GATE(0,7,0x01,0x01)
    // layer 1 (masks = cols of A, parities = rows of A^-1)
    GATE(1,0,0xC0,0x7F) GATE(1,1,0x60,0xC0) GATE(1,2,0x30,0xE0) GATE(1,3,0x18,0xF0)
    GATE(1,4,0x0C,0xF8) GATE(1,5,0x06,0xFC) GATE(1,6,0x03,0xFE) GATE(1,7,0xC1,0xFF)
    // layer 2 (masks = cols of A^2, parities = rows of A^-2)
    GATE(2,0,0xA0,0xD5) GATE(2,1,0x50,0xBF) GATE(2,2,0x28,0x5F) GATE(2,3,0x14,0xAF)
    GATE(2,4,0x0A,0x57) GATE(2,5,0x05,0xAB) GATE(2,6,0xC2,0x55) GATE(2,7,0x61,0xAA)
#undef GATE

    // ---- <Z_0> with final labeling: sign = parity(x & 0x4C) (row7 of A^-3) ----
    float m0 = sr[0]*sr[0] + si[0]*si[0] + sr[2]*sr[2] + si[2]*si[2]; // hi&1==0
    float m1 = sr[1]*sr[1] + si[1]*si[1] + sr[3]*sr[3] + si[3]*si[3]; // hi&1==1
    bool pb = (__popc(lane & 0x0C) & 1) != 0;
    float e = pb ? (m1 - m0) : (m0 - m1);
    e = wred(e, lane);

    // ---- decoder ----
    float acc = 0.f;
#pragma unroll
    for (int m = 0; m < 4; m++) {
        int j = lane + 64 * m;
        float d = fmaxf(fmaf(e, dw1[j], db1[j]), 0.f);
        acc = fmaf(d, dw2[j], acc);
    }
    acc = wred(acc, lane);
    if (lane == 0) out[row] = 1.f / (1.f + __expf(-(acc + db2[0])));
}

extern "C" void kernel_launch(void* const* d_in, const int* in_sizes, int n_in,
                              void* d_out, int out_size, void* d_ws, size_t ws_size,
                              hipStream_t stream) {
    const float* x   = (const float*)d_in[0];
    const float* w1  = (const float*)d_in[1];
    const float* b1  = (const float*)d_in[2];
    const float* w2  = (const float*)d_in[3];
    const float* b2  = (const float*)d_in[4];
    const float* qp  = (const float*)d_in[5];
    const float* dw1 = (const float*)d_in[6];
    const float* db1 = (const float*)d_in[7];
    const float* dw2 = (const float*)d_in[8];
    const float* db2 = (const float*)d_in[9];
    float* out = (float*)d_out;

    const int B = in_sizes[0] / FDIM;
    const int grid = (B + WAVES_PER_BLOCK - 1) / WAVES_PER_BLOCK;
    hqcl_kernel<<<grid, THREADS, 0, stream>>>(x, w1, b1, w2, b2, qp, dw1, db1, dw2, db2, out, B);
}